// Round 14
// baseline (151.589 us; speedup 1.0000x reference)
//
#include <hip/hip_runtime.h>
#include <hip/hip_bf16.h>

// B=4, H=W=56, C=256, 7x7 windows of 8x8, 8 heads x 32, top-4.
// Inputs fp32; d_out fp32. Intermediates bf16; MFMA bf16 w/ fp32 accum.
// 5-launch pipeline: prep -> [qkv_gemm|winproj] -> [route|lepe] -> attn -> proj
// qkv workspace layout: [pix][ Q(256) | head0:K32,V32 | ... | head7:K32,V32 ]
// so each (pixel, head) K+V gather is ONE contiguous 128B cacheline.
#define NPIX 12544   // B*56*56

typedef short bf16x8 __attribute__((ext_vector_type(8)));
typedef short bf16x4 __attribute__((ext_vector_type(4)));
typedef float f32x4  __attribute__((ext_vector_type(4)));

__device__ __forceinline__ float bf2f(unsigned short u) {
    unsigned int x = ((unsigned int)u) << 16;
    float f; __builtin_memcpy(&f, &x, sizeof(f)); return f;
}
__device__ __forceinline__ unsigned short f2bf(float f) {
    __hip_bfloat16 h = __float2bfloat16(f);
    unsigned short u; __builtin_memcpy(&u, &h, 2); return u;
}
// async global->LDS DMA, 16B per lane; LDS dest is wave-uniform base + lane*16
// (global src may be per-lane — used below for the gathered K rows).
__device__ __forceinline__ void load_lds16(const unsigned short* g, unsigned short* l) {
    __builtin_amdgcn_global_load_lds(
        (const __attribute__((address_space(1))) unsigned int*)g,
        (__attribute__((address_space(3))) unsigned int*)l,
        16, 0, 0);
}
// LDS byte offset of a generic pointer known to point into LDS
__device__ __forceinline__ unsigned ldsoff(const void* p) {
    return (unsigned)(unsigned long long)(const __attribute__((address_space(3))) char*)p;
}
// hardware transpose read (stride-16 bf16 tiles), see m156 layout
template<int OFF>
__device__ __forceinline__ bf16x4 tr16(unsigned addr) {
    bf16x4 d;
    asm volatile("ds_read_b64_tr_b16 %0, %1 offset:%c2"
                 : "=v"(d) : "v"(addr), "i"(OFF));
    return d;
}

// ---------------------------------------------------------------------------
// K0: fused prep.
//   blocks 0..391   : x -> bf16 + per-window mean (2 blocks/window, 128 ch each)
//   blocks 392..439 : Wqkv^T tiles (64x64 LDS transpose)
//   blocks 440..455 : Wo^T tiles
// ---------------------------------------------------------------------------
__global__ __launch_bounds__(256) void k_prep(
    const float* __restrict__ X, unsigned short* __restrict__ Xb,
    float* __restrict__ xmean,
    const float* __restrict__ Wqkv, const float* __restrict__ Wo,
    unsigned short* __restrict__ Wtq, unsigned short* __restrict__ Wto)
{
    __shared__ __align__(16) unsigned char sm[64 * 65 * 4];   // 16.6 KB union
    const int t = threadIdx.x;
    const int blk = blockIdx.x;
    if (blk < 392) {
        float* part = (float*)sm;                 // [8 ps][32 cg][4]
        const int w = blk >> 1, hc = blk & 1;
        const int b = w / 49, p = w % 49;
        const int wi = p / 7, wj = p % 7;
        const int ch0 = hc * 128;
        const int ps = t >> 5, cg = t & 31;
        float4 s = {0.f, 0.f, 0.f, 0.f};
        #pragma unroll
        for (int i = 0; i < 8; i++) {
            int pp = ps * 8 + i;
            int y = wi * 8 + (pp >> 3), x = wj * 8 + (pp & 7);
            int idx = (((b * 56) + y) * 56 + x) * 256 + ch0 + cg * 4;
            float4 v = *reinterpret_cast<const float4*>(X + idx);
            s.x += v.x; s.y += v.y; s.z += v.z; s.w += v.w;
            ushort4 o = { f2bf(v.x), f2bf(v.y), f2bf(v.z), f2bf(v.w) };
            *reinterpret_cast<ushort4*>(Xb + idx) = o;
        }
        *reinterpret_cast<float4*>(part + t * 4) = *reinterpret_cast<float4*>(&s);
        __syncthreads();
        if (t < 32) {
            float4 m = {0.f, 0.f, 0.f, 0.f};
            #pragma unroll
            for (int ps2 = 0; ps2 < 8; ps2++) {
                float4 v = *reinterpret_cast<float4*>(part + (ps2 * 32 + t) * 4);
                m.x += v.x; m.y += v.y; m.z += v.z; m.w += v.w;
            }
            m.x *= (1.f / 64.f); m.y *= (1.f / 64.f);
            m.z *= (1.f / 64.f); m.w *= (1.f / 64.f);
            *reinterpret_cast<float4*>(xmean + w * 256 + ch0 + t * 4) = m;
        }
    } else {
        float* tile = (float*)sm;                 // [64][65]
        int tb = blk - 392;
        const float* Wsrc; unsigned short* Wdst; int N, kt, nt;
        if (tb < 48) { Wsrc = Wqkv; Wdst = Wtq; N = 768; kt = tb / 12; nt = tb % 12; }
        else { tb -= 48; Wsrc = Wo; Wdst = Wto; N = 256; kt = tb / 4; nt = tb % 4; }
        const int k0 = kt * 64, n0 = nt * 64;
        const int r0 = t >> 6, c = t & 63;
        #pragma unroll
        for (int i = 0; i < 16; i++) {
            int r = i * 4 + r0;
            tile[r * 65 + c] = Wsrc[(size_t)(k0 + r) * N + n0 + c];
        }
        __syncthreads();
        #pragma unroll
        for (int i = 0; i < 16; i++) {
            int n = i * 4 + r0;
            Wdst[(size_t)(n0 + n) * 256 + k0 + c] = f2bf(tile[c * 65 + n]);
        }
    }
}

// ---------------------------------------------------------------------------
// K1: merged launch — qkv GEMM (blocks 0..1175, 64x128 tiles, dbuf 2-phase)
//                   | winproj (blocks 1176..1567)
// GEMM stores remap to the interleaved layout:
//   n<256: Q, phys=n;  256..511: K, phys=256+hd*64+(n&31);  512..767: V,
//   phys=288+hd*64+(n&31).
// ---------------------------------------------------------------------------
__global__ __launch_bounds__(256) void k_main1(
    const unsigned short* __restrict__ A,   // xb [12544][256]
    const unsigned short* __restrict__ Bt,  // Wtq [768][256]
    const float* __restrict__ bias,         // bqkv [768]
    unsigned short* __restrict__ O,         // qkv bf16 (interleaved layout)
    const float* __restrict__ xmean,
    const float* __restrict__ Wqkv,         // fp32 [256][768]
    float* __restrict__ qwin, float* __restrict__ kwin)
{
    __shared__ __align__(16) unsigned char sm1[24576];
    const int t = threadIdx.x;
    const int blk = blockIdx.x;
    if (blk < 1176) {
        unsigned short* As = (unsigned short*)sm1;           // 2 x [64*32]  =  8 KB
        unsigned short* Bs = (unsigned short*)(sm1 + 8192);  // 2 x [128*32] = 16 KB
        const int m0 = (blk % 196) * 64, n0 = (blk / 196) * 128;
        const int wave = t >> 6, lane = t & 63, quad = lane >> 4, lo = lane & 15;
        const int sr = wave * 16 + (lane >> 2);   // 0..63
        const int sc = lane & 3;
        f32x4 acc[4][2];
        #pragma unroll
        for (int i = 0; i < 4; i++)
            #pragma unroll
            for (int j = 0; j < 2; j++) acc[i][j] = (f32x4){0.f, 0.f, 0.f, 0.f};

        // 2-phase double-buffered K-loop: counted vmcnt, loads fly under MFMA.
        auto stage = [&](int it) {
            int kt = it * 32;
            unsigned short* Ad = As + (it & 1) * 2048;
            unsigned short* Bd = Bs + (it & 1) * 4096;
            {
                int e = sc ^ ((sr >> 1) & 3);
                load_lds16(A + (size_t)(m0 + sr) * 256 + kt + e * 8, &Ad[sr * 32 + sc * 8]);
            }
            #pragma unroll
            for (int j = 0; j < 2; j++) {
                int row = j * 64 + sr;
                int e = sc ^ ((row >> 1) & 3);
                load_lds16(Bt + (size_t)(n0 + row) * 256 + kt + e * 8, &Bd[row * 32 + sc * 8]);
            }
        };
        stage(0);
        for (int it = 0; it < 8; ++it) {
            if (it < 7) {
                stage(it + 1);                                   // 3 loads in flight
                asm volatile("s_waitcnt vmcnt(3)" ::: "memory"); // current buf landed
            } else {
                asm volatile("s_waitcnt vmcnt(0)" ::: "memory");
            }
            __builtin_amdgcn_s_barrier();
            const unsigned short* Ac = As + (it & 1) * 2048;
            const unsigned short* Bc = Bs + (it & 1) * 4096;
            bf16x8 af[4], bfr[2];
            #pragma unroll
            for (int mt = 0; mt < 4; mt++) {
                int row = mt * 16 + lo;
                int c = quad ^ ((row >> 1) & 3);
                af[mt] = *reinterpret_cast<const bf16x8*>(&Ac[row * 32 + c * 8]);
            }
            #pragma unroll
            for (int nt = 0; nt < 2; nt++) {
                int col = wave * 32 + nt * 16 + lo;
                int c = quad ^ ((col >> 1) & 3);
                bfr[nt] = *reinterpret_cast<const bf16x8*>(&Bc[col * 32 + c * 8]);
            }
            #pragma unroll
            for (int mt = 0; mt < 4; mt++)
                #pragma unroll
                for (int nt = 0; nt < 2; nt++)
                    acc[mt][nt] = __builtin_amdgcn_mfma_f32_16x16x32_bf16(
                        af[mt], bfr[nt], acc[mt][nt], 0, 0, 0);
            __builtin_amdgcn_s_barrier();
        }
        float bv[2];
        #pragma unroll
        for (int nt = 0; nt < 2; nt++) bv[nt] = bias[n0 + wave * 32 + nt * 16 + lo];
        #pragma unroll
        for (int mt = 0; mt < 4; mt++)
            #pragma unroll
            for (int nt = 0; nt < 2; nt++) {
                int n = n0 + wave * 32 + nt * 16 + lo;
                // logical column -> interleaved physical column
                int phys;
                if (n < 256)      phys = n;
                else if (n < 512) phys = 256 + ((n - 256) >> 5) * 64 + ((n - 256) & 31);
                else              phys = 288 + ((n - 512) >> 5) * 64 + ((n - 512) & 31);
                #pragma unroll
                for (int r = 0; r < 4; r++) {
                    int m = m0 + mt * 16 + quad * 4 + r;
                    O[m * 768 + phys] = f2bf(acc[mt][nt][r] + bv[nt]);
                }
            }
    } else {
        float* xs = (float*)sm1;                  // [256]
        const int u = blk - 1176;
        const int bp = u % 196;
        const int half = u / 196;                 // 0 -> qwin, 1 -> kwin
        const int c = t;
        xs[c] = xmean[bp * 256 + c];
        __syncthreads();
        const int col = half * 256 + c;
        float a = 0.f;
        for (int k = 0; k < 256; k++) a += xs[k] * Wqkv[k * 768 + col];
        float* outp = half ? kwin : qwin;
        outp[bp * 256 + c] = a + bias[col];
    }
}

// ---------------------------------------------------------------------------
// K2: merged launch — route (blocks 0..195) | lepe (blocks 196..1763)
// lepe lives HERE: folding into k_attn costs ~100 VGPRs (R4/R5); merging
// into the attn LAUNCH costs ~10 us via block-dispatch serialization (R7/R9).
// V read uses the interleaved layout offset.
// ---------------------------------------------------------------------------
__global__ __launch_bounds__(256) void k_main2(
    const float* __restrict__ qwin, const float* __restrict__ kwin,
    int* __restrict__ ridx,
    const unsigned short* __restrict__ QKV,
    const float* __restrict__ lw, const float* __restrict__ lb,
    unsigned short* __restrict__ Olepe)
{
    __shared__ __align__(16) unsigned char sm2[25600];
    const int t = threadIdx.x;
    const int blk = blockIdx.x;
    if (blk < 196) {
        float* part = (float*)sm2;                // [49][4]
        float* lg   = (float*)(sm2 + 49 * 4 * 4); // [49]
        const int b = blk / 49, p = blk % 49;
        if (t < 196) {
            int d = t >> 2, pr = t & 3;
            const float* qp = &qwin[(b * 49 + p) * 256];
            const float* kp = &kwin[(b * 49 + d) * 256];
            float a = 0.f;
            for (int ch = pr * 64; ch < pr * 64 + 64; ch++) a += qp[ch] * kp[ch];
            part[d * 4 + pr] = a;
        }
        __syncthreads();
        if (t < 49) lg[t] = part[t * 4 + 0] + part[t * 4 + 1] + part[t * 4 + 2] + part[t * 4 + 3];
        __syncthreads();
        if (t == 0) {
            unsigned long long used = 0ull;
            for (int sel = 0; sel < 4; sel++) {
                float best = -1e30f; int bi = 0;
                for (int qq = 0; qq < 49; qq++)
                    if (!((used >> qq) & 1ull) && lg[qq] > best) { best = lg[qq]; bi = qq; }
                used |= (1ull << bi);
                ridx[blk * 4 + sel] = bi;
            }
        }
    } else {
        float* lws = (float*)sm2;                 // [25*256]
        #pragma unroll
        for (int i = 0; i < 25; i++) lws[i * 256 + t] = lw[i * 256 + t];

        const int pl = t & 7;
        const int cg = t >> 3;
        const int c0 = cg * 8;
        // interleaved layout: V chans c0..c0+7 live at 256 + (c0>>5)*64 + 32 + (c0&31)
        const int voff = 256 + (cg >> 2) * 64 + 32 + (cg & 3) * 8;
        const int gid = (blk - 196) * 8 + pl;
        const int b = gid / 3136, rem = gid % 3136;
        const int y = rem / 56, x = rem % 56;
        __syncthreads();

        float acc[8];
        {
            float4 b0 = *reinterpret_cast<const float4*>(lb + c0);
            float4 b1 = *reinterpret_cast<const float4*>(lb + c0 + 4);
            acc[0] = b0.x; acc[1] = b0.y; acc[2] = b0.z; acc[3] = b0.w;
            acc[4] = b1.x; acc[5] = b1.y; acc[6] = b1.z; acc[7] = b1.w;
        }
        #pragma unroll
        for (int ky = 0; ky < 5; ky++) {
            int yy = y + ky - 2;
            if (yy < 0 || yy >= 56) continue;
            #pragma unroll
            for (int kx = 0; kx < 5; kx++) {
                int xx = x + kx - 2;
                if (xx < 0 || xx >= 56) continue;
                bf16x8 v = *reinterpret_cast<const bf16x8*>(
                    QKV + (((b * 56) + yy) * 56 + xx) * 768 + voff);
                const float* wrow = &lws[(ky * 5 + kx) * 256 + c0];
                float4 w0 = *reinterpret_cast<const float4*>(wrow);
                float4 w1 = *reinterpret_cast<const float4*>(wrow + 4);
                acc[0] += bf2f((unsigned short)v[0]) * w0.x;
                acc[1] += bf2f((unsigned short)v[1]) * w0.y;
                acc[2] += bf2f((unsigned short)v[2]) * w0.z;
                acc[3] += bf2f((unsigned short)v[3]) * w0.w;
                acc[4] += bf2f((unsigned short)v[4]) * w1.x;
                acc[5] += bf2f((unsigned short)v[5]) * w1.y;
                acc[6] += bf2f((unsigned short)v[6]) * w1.z;
                acc[7] += bf2f((unsigned short)v[7]) * w1.w;
            }
        }
        bf16x8 o;
        #pragma unroll
        for (int j = 0; j < 8; j++) o[j] = (short)f2bf(acc[j]);
        *reinterpret_cast<bf16x8*>(Olepe + (size_t)gid * 256 + c0) = o;
    }
}

// ---------------------------------------------------------------------------
// K6: MFMA gathered window attention (single-pass M=0 softmax).
// Gather: K rows go straight to LDS via global_load_lds (dest Ks[krow*32+c4*8]
// expands to wave-uniform base + lane*16B — the DMA contract; global src is
// the per-lane gathered address). V stays reg-staged (tr16-subtiled dest is
// non-linear in lane, m104). Removes 4 reg-loads + 4 ds_writes per thread
// from the gather phase. LDS = 16384(Vs)+16384(Ks)+8192(PST) = 40960 B.
// ---------------------------------------------------------------------------
__global__ __launch_bounds__(256) void k_attn(
    const unsigned short* __restrict__ QKV,
    const int* __restrict__ ridx,
    const unsigned short* __restrict__ Olepe,
    unsigned short* __restrict__ Osum)
{
    __shared__ __align__(16) unsigned char smem[40960];
    // Vs: V subtiled [k>>2][ch>>4][k&3][ch&15] -> 64*128 shorts = 16 KB
    unsigned short* Vs  = (unsigned short*)smem;
    unsigned short* Ks  = (unsigned short*)(smem + 16384);  // [256][32] = 16 KB
    unsigned short* PST = (unsigned short*)(smem + 32768);  // 4 x 2 KB P^T chunk

    const int p = blockIdx.x, head = blockIdx.y, b = blockIdx.z;
    const int t = threadIdx.x;
    const int wi = p / 7, wj = p % 7;
    const int wave = t >> 6, lane = t & 63, quad = lane >> 4, lo = lane & 15;
    const int pix4 = t >> 2, c4 = t & 3;

    // This thread's output pixel (q = wave*16+lo) and channel slice (quad*8..+8)
    const int q  = wave * 16 + lo;
    const int qy = wi * 8 + (q >> 3), qx = wj * 8 + (q & 7);

    // QK^T A-fragment straight from global (Q layout unchanged)
    bf16x8 af = *reinterpret_cast<const bf16x8*>(
        QKV + (size_t)(((b * 56) + qy) * 56 + qx) * 768 + head * 32 + quad * 8);

    // gather: 4 routed windows; K via LDS-DMA, V reg-staged into tr16 subtiles
    {
        const int4 rs = *reinterpret_cast<const int4*>(&ridx[(b * 49 + p) * 4]);
        const int sels[4] = { rs.x, rs.y, rs.z, rs.w };
        #pragma unroll
        for (int pass = 0; pass < 4; pass++) {
            int sel = sels[pass];
            int si = sel / 7, sj = sel % 7;
            int y = si * 8 + (pix4 >> 3), x = sj * 8 + (pix4 & 7);
            // interleaved: K+V for this head = one 128B block
            const unsigned short* base = QKV + (((b * 56) + y) * 56 + x) * 768 + 256 + head * 64;
            int krow = pass * 64 + pix4;
            load_lds16(base + c4 * 8, &Ks[krow * 32 + c4 * 8]);   // K -> LDS DMA
            bf16x8 vv = *reinterpret_cast<const bf16x8*>(base + 32 + c4 * 8);
            *reinterpret_cast<bf16x8*>(
                &Vs[(krow >> 2) * 128 + (c4 >> 1) * 64 + (krow & 3) * 16 + (c4 & 1) * 8]) = vv;
        }
    }
    __syncthreads();

    const f32x4 z = (f32x4){0.f, 0.f, 0.f, 0.f};

    // ---- single pass: QK^T in 4 chunks of 64 keys; exp (no max); P^T; PV.
    unsigned short* myP = PST + wave * 1024;           // 1024 shorts = 2 KB
    const unsigned pbase = ldsoff(myP) + quad * 256 + lo * 8;
    const unsigned vbase = ldsoff(Vs)  + quad * 512 + lo * 8;
    float l[4] = {0.f, 0.f, 0.f, 0.f};
    f32x4 o0 = z, o1 = z;
    for (int c = 0; c < 4; c++) {
        f32x4 s[4];
        #pragma unroll
        for (int td = 0; td < 4; td++) {
            bf16x8 kf = *reinterpret_cast<const bf16x8*>(
                &Ks[((4 * c + td) * 16 + lo) * 32 + quad * 8]);
            s[td] = __builtin_amdgcn_mfma_f32_16x16x32_bf16(af, kf, z, 0, 0, 0);
        }
        #pragma unroll
        for (int td = 0; td < 4; td++) {
            float e[4];
            #pragma unroll
            for (int r = 0; r < 4; r++) {
                e[r] = __expf(s[td][r] * 0.0625f);
                l[r] += e[r];
            }
            ushort4 pk = { f2bf(e[0]), f2bf(e[1]), f2bf(e[2]), f2bf(e[3]) };
            *reinterpret_cast<ushort4*>(&myP[(td * 16 + lo) * 16 + quad * 4]) = pk;
        }
        asm volatile("s_waitcnt lgkmcnt(0)" ::: "memory");
        __builtin_amdgcn_sched_barrier(0);

        // two 32-key groups: P rows 0..31 (pbase+0/128) and 32..63 (+1024/1152)
        const unsigned vb0a = vbase + (2 * c) * 2048;
        const unsigned vb1a = vbase + (2 * c + 1) * 2048;
        bf16x4 ra0 = tr16<0>(pbase);
        bf16x4 ra1 = tr16<128>(pbase);
        bf16x4 rb0 = tr16<1024>(pbase);
        bf16x4 rb1 = tr16<1152>(pbase);
        bf16x4 w00 = tr16<0>(vb0a),  w01 = tr16<256>(vb0a);
        bf16x4 w10 = tr16<128>(vb0a), w11 = tr16<384>(vb0a);
        bf16x4 x00 = tr16<0>(vb1a),  x01 = tr16<256>(vb1a);
        bf16x4 x10 = tr16<128>(vb1a), x11 = tr16<384>(vb1a);
        asm volatile("s_waitcnt lgkmcnt(0)" ::: "memory");
        __builtin_amdgcn_sched_barrier(0);
        bf16x8 pa, pb, va0, va1, vc0, vc1;
        #pragma unroll
        for (int j = 0; j < 4; j++) {
            pa[j]  = ra0[j]; pa[4 + j]  = ra1[j];
            pb[j]  = rb0[j]; pb[4 + j]  = rb1[j];
            va0[j] = w00[j]; va0[4 + j] = w01[j];
            va1[j] = w10[j]; va1[4 + j] = w11[j];
            vc0[j] = x00[j]; vc0[4 + j] = x01[j];
            vc1[j] = x10[j]; vc1[4 + j] = x11[j];
        }
        o0 = __builtin_amdgcn_mfma_f32_16x16x32_bf16(pa, va0, o0, 0, 0, 0);
        o1 = __builtin_amdgcn_mfma_f32_16x16x32_bf16(pa, va1, o1, 0, 0, 0);
        o0 = __builtin_amdgcn_mfma_f32_16x16x32_bf16(pb, vc0, o0, 0, 0, 0);
        o1 = __builtin_amdgcn_mfma_f32_16x16x32_bf16(pb, vc1, o1, 0, 0, 0);
    }
    #pragma unroll
    for (int d = 1; d < 16; d <<= 1)
        #pragma unroll
        for (int r = 0; r < 4; r++) l[r] += __shfl_xor(l[r], d);

    // Epilogue: bounce O^T through this wave's own (drained) myP region,
    // then one 16B Olepe load + one 16B Osum store per lane.
    {
        float i0 = 1.f / l[0], i1 = 1.f / l[1], i2 = 1.f / l[2], i3 = 1.f / l[3];
        ushort4 p0 = { f2bf(o0[0] * i0), f2bf(o0[1] * i1),
                       f2bf(o0[2] * i2), f2bf(o0[3] * i3) };
        ushort4 p1 = { f2bf(o1[0] * i0), f2bf(o1[1] * i1),
                       f2bf(o1[2] * i2), f2bf(o1[3] * i3) };
        *reinterpret_cast<ushort4*>(&myP[lo * 16 + quad * 4]) = p0;         // ch = lo
        *reinterpret_cast<ushort4*>(&myP[(16 + lo) * 16 + quad * 4]) = p1;  // ch = 16+lo
    }
    const unsigned oaddr = ldsoff(myP) + quad * 256 + lo * 8;
    asm volatile("s_waitcnt lgkmcnt(0)" ::: "memory");
    __builtin_amdgcn_sched_barrier(0);
    bf16x4 e0 = tr16<0>(oaddr);     // ch = quad*8 + 0..3, pixel q = wave*16+lo
    bf16x4 e1 = tr16<128>(oaddr);   // ch = quad*8 + 4..7
    asm volatile("s_waitcnt lgkmcnt(0)" ::: "memory");
    __builtin_amdgcn_sched_barrier(0);
    {
        size_t gbase = (size_t)(((b * 56) + qy) * 56 + qx) * 256 + head * 32 + quad * 8;
        bf16x8 lp = *reinterpret_cast<const bf16x8*>(Olepe + gbase);
        bf16x8 oo;
        #pragma unroll
        for (int j = 0; j < 4; j++) {
            oo[j]     = (short)f2bf(bf2f((unsigned short)e0[j]) + bf2f((unsigned short)lp[j]));
            oo[4 + j] = (short)f2bf(bf2f((unsigned short)e1[j]) + bf2f((unsigned short)lp[4 + j]));
        }
        *reinterpret_cast<bf16x8*>(Osum + gbase) = oo;
    }
}

// ---------------------------------------------------------------------------
// K7: out proj (MFMA, double-buffered DMA): Osum[12544,256] @ Wo^T + bo.
// M-tile 64 -> 784 blocks (3.06/CU): no tail quantization (R8 lesson).
// ---------------------------------------------------------------------------
__global__ __launch_bounds__(256) void k_proj(
    const unsigned short* __restrict__ A,
    const unsigned short* __restrict__ Bt,   // Wto [256][256]
    const float* __restrict__ bias,
    float* __restrict__ O)
{
    __shared__ __align__(16) unsigned short As[2 * 64 * 32];
    __shared__ __align__(16) unsigned short Bs[2 * 64 * 32];
    const int t = threadIdx.x;
    const int m0 = blockIdx.x * 64, n0 = blockIdx.y * 64;
    const int wave = t >> 6, lane = t & 63, quad = lane >> 4, lo = lane & 15;
    const int sr = wave * 16 + (lane >> 2);
    const int sc = lane & 3;
    f32x4 acc[4];
    #pragma unroll
    for (int j = 0; j < 4; j++) acc[j] = (f32x4){0.f, 0.f, 0.f, 0.f};

    auto stage = [&](int it) {
        int kt = it * 32;
        unsigned short* Ad = As + (it & 1) * 2048;
        unsigned short* Bd = Bs + (it & 1) * 2048;
        int e = sc ^ ((sr >> 1) & 3);
        load_lds16(A  + (size_t)(m0 + sr) * 256 + kt + e * 8, &Ad[sr * 32 + sc * 8]);
        load_lds16(Bt + (size_t)(n0 + sr) * 256 + kt + e * 8, &Bd[sr * 32 + sc * 8]);
    };
    stage(0);
    for (int it = 0; it < 8; ++it) {
        if (it < 7) {
            stage(it + 1);                                   // 2 loads in flight
            asm volatile("s_waitcnt vmcnt(2)" ::: "memory");
        } else {
            asm volatile("s_waitcnt vmcnt(0)" ::: "memory");
        }
        __builtin_amdgcn_s_barrier();
        const unsigned short* Ac = As + (it & 1) * 2048;
        const unsigned short* Bc = Bs + (it & 1) * 2048;
        bf16x8 af;
        {
            int row = wave * 16 + lo;
            int c = quad ^ ((row >> 1) & 3);
            af = *reinterpret_cast<const bf16x8*>(&Ac[row * 32 + c * 8]);
        }
        bf16x8 bfr[4];
        #pragma unroll
        for (int nt = 0; nt < 4; nt++) {
            int col = nt * 16 + lo;
            int c = quad ^ ((col >> 1) & 3);
            bfr[nt] = *reinterpret_cast<const bf16x8*>(&Bc[col * 32 + c * 8]);
        }
        #pragma unroll
        for (int nt = 0; nt < 4; nt++)
            acc[nt] = __builtin_amdgcn_mfma_f32_16x16x32_bf16(af, bfr[nt], acc[nt], 0, 0, 0);
        __builtin_amdgcn_s_barrier();
    }
    float bv[4];
    #pragma unroll
    for (int nt = 0; nt < 4; nt++) bv[nt] = bias[n0 + nt * 16 + lo];
    #pragma unroll
    for (int nt = 0; nt < 4; nt++) {
        int n = n0 + nt * 16 + lo;
        #pragma unroll
        for (int r = 0; r < 4; r++) {
            int m = m0 + wave * 16 + quad * 4 + r;
            O[m * 256 + n] = acc[nt][r] + bv[nt];
        }
    }
}

// ---------------------------------------------------------------------------
extern "C" void kernel_launch(void* const* d_in, const int* in_sizes, int n_in,
                              void* d_out, int out_size, void* d_ws, size_t ws_size,
                              hipStream_t stream)
{
    const float* x    = (const float*)d_in[0];
    const float* Wqkv = (const float*)d_in[1];
    const float* bqkv = (const float*)d_in[2];
    const float* Wo   = (const float*)d_in[3];
    const float* bo   = (const float*)d_in[4];
    const float* lw   = (const float*)d_in[5];
    const float* lb   = (const float*)d_in[6];
    float* out = (float*)d_out;

    char* ws = (char*)d_ws;
    size_t off = 0;
    unsigned short* qkv   = (unsigned short*)(ws + off); off += (size_t)NPIX * 768 * 2;
    unsigned short* xb    = (unsigned short*)(ws + off); off += (size_t)NPIX * 256 * 2;
    unsigned short* Wtq   = (unsigned short*)(ws + off); off += 768 * 256 * 2;
    unsigned short* Wto   = (unsigned short*)(ws + off); off += 256 * 256 * 2;
    unsigned short* Osum  = (unsigned short*)(ws + off); off += (size_t)NPIX * 256 * 2;
    unsigned short* Olepe = (unsigned short*)(ws + off); off += (size_t)NPIX * 256 * 2;
    float* xmean = (float*)(ws + off); off += 196 * 256 * 4;
    float* qwin  = (float*)(ws + off); off += 196 * 256 * 4;
    float* kwin  = (float*)(ws + off); off += 196 * 256 * 4;
    int*   ridx  = (int*)(ws + off);   off += 196 * 4 * 4;

    k_prep <<<dim3(456),      256, 0, stream>>>(x, xb, xmean, Wqkv, Wo, Wtq, Wto);
    k_main1<<<dim3(1568),     256, 0, stream>>>(xb, Wtq, bqkv, qkv, xmean, Wqkv, qwin, kwin);
    k_main2<<<dim3(1764),     256, 0, stream>>>(qwin, kwin, ridx, qkv, lw, lb, Olepe);
    k_attn <<<dim3(49, 8, 4), 256, 0, stream>>>(qkv, ridx, Olepe, Osum);
    k_proj <<<dim3(196, 4),   256, 0, stream>>>(Osum, Wto, bo, out);
}

// Round 15
// 147.749 us; speedup vs baseline: 1.0260x; 1.0260x over previous
//
#include <hip/hip_runtime.h>
#include <hip/hip_bf16.h>

// B=4, H=W=56, C=256, 7x7 windows of 8x8, 8 heads x 32, top-4.
// Inputs fp32; d_out fp32. Intermediates bf16; MFMA bf16 w/ fp32 accum.
// 5-launch pipeline: prep -> [qkv_gemm|winproj] -> [route|lepe] -> attn -> proj
// qkv workspace layout: [pix][ Q(256) | head0:K32,V32 | ... | head7:K32,V32 ]
// so each (pixel, head) K+V gather is ONE contiguous 128B cacheline.
// R14 lesson: K-gather via global_load_lds REGRESSED (+2.9us) — DMA against
// scattered lines + splitting the shared K|V line into two op types doubles
// L2 requests. Gather stays reg-staged (this file = R12, the 148.7us best).
#define NPIX 12544   // B*56*56

typedef short bf16x8 __attribute__((ext_vector_type(8)));
typedef short bf16x4 __attribute__((ext_vector_type(4)));
typedef float f32x4  __attribute__((ext_vector_type(4)));

__device__ __forceinline__ float bf2f(unsigned short u) {
    unsigned int x = ((unsigned int)u) << 16;
    float f; __builtin_memcpy(&f, &x, sizeof(f)); return f;
}
__device__ __forceinline__ unsigned short f2bf(float f) {
    __hip_bfloat16 h = __float2bfloat16(f);
    unsigned short u; __builtin_memcpy(&u, &h, 2); return u;
}
// async global->LDS DMA, 16B per lane; LDS dest is wave-uniform base + lane*16
__device__ __forceinline__ void load_lds16(const unsigned short* g, unsigned short* l) {
    __builtin_amdgcn_global_load_lds(
        (const __attribute__((address_space(1))) unsigned int*)g,
        (__attribute__((address_space(3))) unsigned int*)l,
        16, 0, 0);
}
// LDS byte offset of a generic pointer known to point into LDS
__device__ __forceinline__ unsigned ldsoff(const void* p) {
    return (unsigned)(unsigned long long)(const __attribute__((address_space(3))) char*)p;
}
// hardware transpose read (stride-16 bf16 tiles), see m156 layout
template<int OFF>
__device__ __forceinline__ bf16x4 tr16(unsigned addr) {
    bf16x4 d;
    asm volatile("ds_read_b64_tr_b16 %0, %1 offset:%c2"
                 : "=v"(d) : "v"(addr), "i"(OFF));
    return d;
}

// ---------------------------------------------------------------------------
// K0: fused prep.
//   blocks 0..391   : x -> bf16 + per-window mean (2 blocks/window, 128 ch each)
//   blocks 392..439 : Wqkv^T tiles (64x64 LDS transpose)
//   blocks 440..455 : Wo^T tiles
// ---------------------------------------------------------------------------
__global__ __launch_bounds__(256) void k_prep(
    const float* __restrict__ X, unsigned short* __restrict__ Xb,
    float* __restrict__ xmean,
    const float* __restrict__ Wqkv, const float* __restrict__ Wo,
    unsigned short* __restrict__ Wtq, unsigned short* __restrict__ Wto)
{
    __shared__ __align__(16) unsigned char sm[64 * 65 * 4];   // 16.6 KB union
    const int t = threadIdx.x;
    const int blk = blockIdx.x;
    if (blk < 392) {
        float* part = (float*)sm;                 // [8 ps][32 cg][4]
        const int w = blk >> 1, hc = blk & 1;
        const int b = w / 49, p = w % 49;
        const int wi = p / 7, wj = p % 7;
        const int ch0 = hc * 128;
        const int ps = t >> 5, cg = t & 31;
        float4 s = {0.f, 0.f, 0.f, 0.f};
        #pragma unroll
        for (int i = 0; i < 8; i++) {
            int pp = ps * 8 + i;
            int y = wi * 8 + (pp >> 3), x = wj * 8 + (pp & 7);
            int idx = (((b * 56) + y) * 56 + x) * 256 + ch0 + cg * 4;
            float4 v = *reinterpret_cast<const float4*>(X + idx);
            s.x += v.x; s.y += v.y; s.z += v.z; s.w += v.w;
            ushort4 o = { f2bf(v.x), f2bf(v.y), f2bf(v.z), f2bf(v.w) };
            *reinterpret_cast<ushort4*>(Xb + idx) = o;
        }
        *reinterpret_cast<float4*>(part + t * 4) = *reinterpret_cast<float4*>(&s);
        __syncthreads();
        if (t < 32) {
            float4 m = {0.f, 0.f, 0.f, 0.f};
            #pragma unroll
            for (int ps2 = 0; ps2 < 8; ps2++) {
                float4 v = *reinterpret_cast<float4*>(part + (ps2 * 32 + t) * 4);
                m.x += v.x; m.y += v.y; m.z += v.z; m.w += v.w;
            }
            m.x *= (1.f / 64.f); m.y *= (1.f / 64.f);
            m.z *= (1.f / 64.f); m.w *= (1.f / 64.f);
            *reinterpret_cast<float4*>(xmean + w * 256 + ch0 + t * 4) = m;
        }
    } else {
        float* tile = (float*)sm;                 // [64][65]
        int tb = blk - 392;
        const float* Wsrc; unsigned short* Wdst; int N, kt, nt;
        if (tb < 48) { Wsrc = Wqkv; Wdst = Wtq; N = 768; kt = tb / 12; nt = tb % 12; }
        else { tb -= 48; Wsrc = Wo; Wdst = Wto; N = 256; kt = tb / 4; nt = tb % 4; }
        const int k0 = kt * 64, n0 = nt * 64;
        const int r0 = t >> 6, c = t & 63;
        #pragma unroll
        for (int i = 0; i < 16; i++) {
            int r = i * 4 + r0;
            tile[r * 65 + c] = Wsrc[(size_t)(k0 + r) * N + n0 + c];
        }
        __syncthreads();
        #pragma unroll
        for (int i = 0; i < 16; i++) {
            int n = i * 4 + r0;
            Wdst[(size_t)(n0 + n) * 256 + k0 + c] = f2bf(tile[c * 65 + n]);
        }
    }
}

// ---------------------------------------------------------------------------
// K1: merged launch — qkv GEMM (blocks 0..1175, 64x128 tiles, dbuf 2-phase)
//                   | winproj (blocks 1176..1567)
// GEMM stores remap to the interleaved layout:
//   n<256: Q, phys=n;  256..511: K, phys=256+hd*64+(n&31);  512..767: V,
//   phys=288+hd*64+(n&31).
// ---------------------------------------------------------------------------
__global__ __launch_bounds__(256) void k_main1(
    const unsigned short* __restrict__ A,   // xb [12544][256]
    const unsigned short* __restrict__ Bt,  // Wtq [768][256]
    const float* __restrict__ bias,         // bqkv [768]
    unsigned short* __restrict__ O,         // qkv bf16 (interleaved layout)
    const float* __restrict__ xmean,
    const float* __restrict__ Wqkv,         // fp32 [256][768]
    float* __restrict__ qwin, float* __restrict__ kwin)
{
    __shared__ __align__(16) unsigned char sm1[24576];
    const int t = threadIdx.x;
    const int blk = blockIdx.x;
    if (blk < 1176) {
        unsigned short* As = (unsigned short*)sm1;           // 2 x [64*32]  =  8 KB
        unsigned short* Bs = (unsigned short*)(sm1 + 8192);  // 2 x [128*32] = 16 KB
        const int m0 = (blk % 196) * 64, n0 = (blk / 196) * 128;
        const int wave = t >> 6, lane = t & 63, quad = lane >> 4, lo = lane & 15;
        const int sr = wave * 16 + (lane >> 2);   // 0..63
        const int sc = lane & 3;
        f32x4 acc[4][2];
        #pragma unroll
        for (int i = 0; i < 4; i++)
            #pragma unroll
            for (int j = 0; j < 2; j++) acc[i][j] = (f32x4){0.f, 0.f, 0.f, 0.f};

        // 2-phase double-buffered K-loop: counted vmcnt, loads fly under MFMA.
        auto stage = [&](int it) {
            int kt = it * 32;
            unsigned short* Ad = As + (it & 1) * 2048;
            unsigned short* Bd = Bs + (it & 1) * 4096;
            {
                int e = sc ^ ((sr >> 1) & 3);
                load_lds16(A + (size_t)(m0 + sr) * 256 + kt + e * 8, &Ad[sr * 32 + sc * 8]);
            }
            #pragma unroll
            for (int j = 0; j < 2; j++) {
                int row = j * 64 + sr;
                int e = sc ^ ((row >> 1) & 3);
                load_lds16(Bt + (size_t)(n0 + row) * 256 + kt + e * 8, &Bd[row * 32 + sc * 8]);
            }
        };
        stage(0);
        for (int it = 0; it < 8; ++it) {
            if (it < 7) {
                stage(it + 1);                                   // 3 loads in flight
                asm volatile("s_waitcnt vmcnt(3)" ::: "memory"); // current buf landed
            } else {
                asm volatile("s_waitcnt vmcnt(0)" ::: "memory");
            }
            __builtin_amdgcn_s_barrier();
            const unsigned short* Ac = As + (it & 1) * 2048;
            const unsigned short* Bc = Bs + (it & 1) * 4096;
            bf16x8 af[4], bfr[2];
            #pragma unroll
            for (int mt = 0; mt < 4; mt++) {
                int row = mt * 16 + lo;
                int c = quad ^ ((row >> 1) & 3);
                af[mt] = *reinterpret_cast<const bf16x8*>(&Ac[row * 32 + c * 8]);
            }
            #pragma unroll
            for (int nt = 0; nt < 2; nt++) {
                int col = wave * 32 + nt * 16 + lo;
                int c = quad ^ ((col >> 1) & 3);
                bfr[nt] = *reinterpret_cast<const bf16x8*>(&Bc[col * 32 + c * 8]);
            }
            #pragma unroll
            for (int mt = 0; mt < 4; mt++)
                #pragma unroll
                for (int nt = 0; nt < 2; nt++)
                    acc[mt][nt] = __builtin_amdgcn_mfma_f32_16x16x32_bf16(
                        af[mt], bfr[nt], acc[mt][nt], 0, 0, 0);
            __builtin_amdgcn_s_barrier();
        }
        float bv[2];
        #pragma unroll
        for (int nt = 0; nt < 2; nt++) bv[nt] = bias[n0 + wave * 32 + nt * 16 + lo];
        #pragma unroll
        for (int mt = 0; mt < 4; mt++)
            #pragma unroll
            for (int nt = 0; nt < 2; nt++) {
                int n = n0 + wave * 32 + nt * 16 + lo;
                // logical column -> interleaved physical column
                int phys;
                if (n < 256)      phys = n;
                else if (n < 512) phys = 256 + ((n - 256) >> 5) * 64 + ((n - 256) & 31);
                else              phys = 288 + ((n - 512) >> 5) * 64 + ((n - 512) & 31);
                #pragma unroll
                for (int r = 0; r < 4; r++) {
                    int m = m0 + mt * 16 + quad * 4 + r;
                    O[m * 768 + phys] = f2bf(acc[mt][nt][r] + bv[nt]);
                }
            }
    } else {
        float* xs = (float*)sm1;                  // [256]
        const int u = blk - 1176;
        const int bp = u % 196;
        const int half = u / 196;                 // 0 -> qwin, 1 -> kwin
        const int c = t;
        xs[c] = xmean[bp * 256 + c];
        __syncthreads();
        const int col = half * 256 + c;
        float a = 0.f;
        for (int k = 0; k < 256; k++) a += xs[k] * Wqkv[k * 768 + col];
        float* outp = half ? kwin : qwin;
        outp[bp * 256 + c] = a + bias[col];
    }
}

// ---------------------------------------------------------------------------
// K2: merged launch — route (blocks 0..195) | lepe (blocks 196..1763)
// lepe lives HERE: folding into k_attn costs ~100 VGPRs (R4/R5); merging
// into the attn LAUNCH costs ~10 us via block-dispatch serialization (R7/R9).
// V read uses the interleaved layout offset.
// ---------------------------------------------------------------------------
__global__ __launch_bounds__(256) void k_main2(
    const float* __restrict__ qwin, const float* __restrict__ kwin,
    int* __restrict__ ridx,
    const unsigned short* __restrict__ QKV,
    const float* __restrict__ lw, const float* __restrict__ lb,
    unsigned short* __restrict__ Olepe)
{
    __shared__ __align__(16) unsigned char sm2[25600];
    const int t = threadIdx.x;
    const int blk = blockIdx.x;
    if (blk < 196) {
        float* part = (float*)sm2;                // [49][4]
        float* lg   = (float*)(sm2 + 49 * 4 * 4); // [49]
        const int b = blk / 49, p = blk % 49;
        if (t < 196) {
            int d = t >> 2, pr = t & 3;
            const float* qp = &qwin[(b * 49 + p) * 256];
            const float* kp = &kwin[(b * 49 + d) * 256];
            float a = 0.f;
            for (int ch = pr * 64; ch < pr * 64 + 64; ch++) a += qp[ch] * kp[ch];
            part[d * 4 + pr] = a;
        }
        __syncthreads();
        if (t < 49) lg[t] = part[t * 4 + 0] + part[t * 4 + 1] + part[t * 4 + 2] + part[t * 4 + 3];
        __syncthreads();
        if (t == 0) {
            unsigned long long used = 0ull;
            for (int sel = 0; sel < 4; sel++) {
                float best = -1e30f; int bi = 0;
                for (int qq = 0; qq < 49; qq++)
                    if (!((used >> qq) & 1ull) && lg[qq] > best) { best = lg[qq]; bi = qq; }
                used |= (1ull << bi);
                ridx[blk * 4 + sel] = bi;
            }
        }
    } else {
        float* lws = (float*)sm2;                 // [25*256]
        #pragma unroll
        for (int i = 0; i < 25; i++) lws[i * 256 + t] = lw[i * 256 + t];

        const int pl = t & 7;
        const int cg = t >> 3;
        const int c0 = cg * 8;
        // interleaved layout: V chans c0..c0+7 live at 256 + (c0>>5)*64 + 32 + (c0&31)
        const int voff = 256 + (cg >> 2) * 64 + 32 + (cg & 3) * 8;
        const int gid = (blk - 196) * 8 + pl;
        const int b = gid / 3136, rem = gid % 3136;
        const int y = rem / 56, x = rem % 56;
        __syncthreads();

        float acc[8];
        {
            float4 b0 = *reinterpret_cast<const float4*>(lb + c0);
            float4 b1 = *reinterpret_cast<const float4*>(lb + c0 + 4);
            acc[0] = b0.x; acc[1] = b0.y; acc[2] = b0.z; acc[3] = b0.w;
            acc[4] = b1.x; acc[5] = b1.y; acc[6] = b1.z; acc[7] = b1.w;
        }
        #pragma unroll
        for (int ky = 0; ky < 5; ky++) {
            int yy = y + ky - 2;
            if (yy < 0 || yy >= 56) continue;
            #pragma unroll
            for (int kx = 0; kx < 5; kx++) {
                int xx = x + kx - 2;
                if (xx < 0 || xx >= 56) continue;
                bf16x8 v = *reinterpret_cast<const bf16x8*>(
                    QKV + (((b * 56) + yy) * 56 + xx) * 768 + voff);
                const float* wrow = &lws[(ky * 5 + kx) * 256 + c0];
                float4 w0 = *reinterpret_cast<const float4*>(wrow);
                float4 w1 = *reinterpret_cast<const float4*>(wrow + 4);
                acc[0] += bf2f((unsigned short)v[0]) * w0.x;
                acc[1] += bf2f((unsigned short)v[1]) * w0.y;
                acc[2] += bf2f((unsigned short)v[2]) * w0.z;
                acc[3] += bf2f((unsigned short)v[3]) * w0.w;
                acc[4] += bf2f((unsigned short)v[4]) * w1.x;
                acc[5] += bf2f((unsigned short)v[5]) * w1.y;
                acc[6] += bf2f((unsigned short)v[6]) * w1.z;
                acc[7] += bf2f((unsigned short)v[7]) * w1.w;
            }
        }
        bf16x8 o;
        #pragma unroll
        for (int j = 0; j < 8; j++) o[j] = (short)f2bf(acc[j]);
        *reinterpret_cast<bf16x8*>(Olepe + (size_t)gid * 256 + c0) = o;
    }
}

// ---------------------------------------------------------------------------
// K6: MFMA gathered window attention (single-pass M=0 softmax).
// Gather reads K+V for (pixel, head) as ONE contiguous 128B block:
// K at +256+head*64, V at +32 more — full-cacheline utilization on the
// latency-bound gather. Reg-staged (DMA variant regressed, R14).
// LDS = 16384(Vs)+16384(Ks)+8192(PST) = 40960 B.
// ---------------------------------------------------------------------------
__global__ __launch_bounds__(256) void k_attn(
    const unsigned short* __restrict__ QKV,
    const int* __restrict__ ridx,
    const unsigned short* __restrict__ Olepe,
    unsigned short* __restrict__ Osum)
{
    __shared__ __align__(16) unsigned char smem[40960];
    // Vs: V subtiled [k>>2][ch>>4][k&3][ch&15] -> 64*128 shorts = 16 KB
    unsigned short* Vs  = (unsigned short*)smem;
    unsigned short* Ks  = (unsigned short*)(smem + 16384);  // [256][32] = 16 KB
    unsigned short* PST = (unsigned short*)(smem + 32768);  // 4 x 2 KB P^T chunk

    const int p = blockIdx.x, head = blockIdx.y, b = blockIdx.z;
    const int t = threadIdx.x;
    const int wi = p / 7, wj = p % 7;
    const int wave = t >> 6, lane = t & 63, quad = lane >> 4, lo = lane & 15;
    const int pix4 = t >> 2, c4 = t & 3;

    // This thread's output pixel (q = wave*16+lo) and channel slice (quad*8..+8)
    const int q  = wave * 16 + lo;
    const int qy = wi * 8 + (q >> 3), qx = wj * 8 + (q & 7);

    // QK^T A-fragment straight from global (Q layout unchanged)
    bf16x8 af = *reinterpret_cast<const bf16x8*>(
        QKV + (size_t)(((b * 56) + qy) * 56 + qx) * 768 + head * 32 + quad * 8);

    // gather: 4 routed windows' K (plain [key][32] tile) and V (tr-read subtiles)
    {
        const int4 rs = *reinterpret_cast<const int4*>(&ridx[(b * 49 + p) * 4]);
        const int sels[4] = { rs.x, rs.y, rs.z, rs.w };
        #pragma unroll
        for (int pass = 0; pass < 4; pass++) {
            int sel = sels[pass];
            int si = sel / 7, sj = sel % 7;
            int y = si * 8 + (pix4 >> 3), x = sj * 8 + (pix4 & 7);
            // interleaved: K+V for this head = one 128B block
            const unsigned short* base = QKV + (((b * 56) + y) * 56 + x) * 768 + 256 + head * 64;
            bf16x8 kv = *reinterpret_cast<const bf16x8*>(base + c4 * 8);
            bf16x8 vv = *reinterpret_cast<const bf16x8*>(base + 32 + c4 * 8);
            int krow = pass * 64 + pix4;
            *reinterpret_cast<bf16x8*>(&Ks[krow * 32 + c4 * 8]) = kv;
            *reinterpret_cast<bf16x8*>(
                &Vs[(krow >> 2) * 128 + (c4 >> 1) * 64 + (krow & 3) * 16 + (c4 & 1) * 8]) = vv;
        }
    }
    __syncthreads();

    const f32x4 z = (f32x4){0.f, 0.f, 0.f, 0.f};

    // ---- single pass: QK^T in 4 chunks of 64 keys; exp (no max); P^T; PV.
    unsigned short* myP = PST + wave * 1024;           // 1024 shorts = 2 KB
    const unsigned pbase = ldsoff(myP) + quad * 256 + lo * 8;
    const unsigned vbase = ldsoff(Vs)  + quad * 512 + lo * 8;
    float l[4] = {0.f, 0.f, 0.f, 0.f};
    f32x4 o0 = z, o1 = z;
    for (int c = 0; c < 4; c++) {
        f32x4 s[4];
        #pragma unroll
        for (int td = 0; td < 4; td++) {
            bf16x8 kf = *reinterpret_cast<const bf16x8*>(
                &Ks[((4 * c + td) * 16 + lo) * 32 + quad * 8]);
            s[td] = __builtin_amdgcn_mfma_f32_16x16x32_bf16(af, kf, z, 0, 0, 0);
        }
        #pragma unroll
        for (int td = 0; td < 4; td++) {
            float e[4];
            #pragma unroll
            for (int r = 0; r < 4; r++) {
                e[r] = __expf(s[td][r] * 0.0625f);
                l[r] += e[r];
            }
            ushort4 pk = { f2bf(e[0]), f2bf(e[1]), f2bf(e[2]), f2bf(e[3]) };
            *reinterpret_cast<ushort4*>(&myP[(td * 16 + lo) * 16 + quad * 4]) = pk;
        }
        asm volatile("s_waitcnt lgkmcnt(0)" ::: "memory");
        __builtin_amdgcn_sched_barrier(0);

        // two 32-key groups: P rows 0..31 (pbase+0/128) and 32..63 (+1024/1152)
        const unsigned vb0a = vbase + (2 * c) * 2048;
        const unsigned vb1a = vbase + (2 * c + 1) * 2048;
        bf16x4 ra0 = tr16<0>(pbase);
        bf16x4 ra1 = tr16<128>(pbase);
        bf16x4 rb0 = tr16<1024>(pbase);
        bf16x4 rb1 = tr16<1152>(pbase);
        bf16x4 w00 = tr16<0>(vb0a),  w01 = tr16<256>(vb0a);
        bf16x4 w10 = tr16<128>(vb0a), w11 = tr16<384>(vb0a);
        bf16x4 x00 = tr16<0>(vb1a),  x01 = tr16<256>(vb1a);
        bf16x4 x10 = tr16<128>(vb1a), x11 = tr16<384>(vb1a);
        asm volatile("s_waitcnt lgkmcnt(0)" ::: "memory");
        __builtin_amdgcn_sched_barrier(0);
        bf16x8 pa, pb, va0, va1, vc0, vc1;
        #pragma unroll
        for (int j = 0; j < 4; j++) {
            pa[j]  = ra0[j]; pa[4 + j]  = ra1[j];
            pb[j]  = rb0[j]; pb[4 + j]  = rb1[j];
            va0[j] = w00[j]; va0[4 + j] = w01[j];
            va1[j] = w10[j]; va1[4 + j] = w11[j];
            vc0[j] = x00[j]; vc0[4 + j] = x01[j];
            vc1[j] = x10[j]; vc1[4 + j] = x11[j];
        }
        o0 = __builtin_amdgcn_mfma_f32_16x16x32_bf16(pa, va0, o0, 0, 0, 0);
        o1 = __builtin_amdgcn_mfma_f32_16x16x32_bf16(pa, va1, o1, 0, 0, 0);
        o0 = __builtin_amdgcn_mfma_f32_16x16x32_bf16(pb, vc0, o0, 0, 0, 0);
        o1 = __builtin_amdgcn_mfma_f32_16x16x32_bf16(pb, vc1, o1, 0, 0, 0);
    }
    #pragma unroll
    for (int d = 1; d < 16; d <<= 1)
        #pragma unroll
        for (int r = 0; r < 4; r++) l[r] += __shfl_xor(l[r], d);

    // Epilogue: bounce O^T through this wave's own (drained) myP region,
    // then one 16B Olepe load + one 16B Osum store per lane.
    {
        float i0 = 1.f / l[0], i1 = 1.f / l[1], i2 = 1.f / l[2], i3 = 1.f / l[3];
        ushort4 p0 = { f2bf(o0[0] * i0), f2bf(o0[1] * i1),
                       f2bf(o0[2] * i2), f2bf(o0[3] * i3) };
        ushort4 p1 = { f2bf(o1[0] * i0), f2bf(o1[1] * i1),
                       f2bf(o1[2] * i2), f2bf(o1[3] * i3) };
        *reinterpret_cast<ushort4*>(&myP[lo * 16 + quad * 4]) = p0;         // ch = lo
        *reinterpret_cast<ushort4*>(&myP[(16 + lo) * 16 + quad * 4]) = p1;  // ch = 16+lo
    }
    const unsigned oaddr = ldsoff(myP) + quad * 256 + lo * 8;
    asm volatile("s_waitcnt lgkmcnt(0)" ::: "memory");
    __builtin_amdgcn_sched_barrier(0);
    bf16x4 e0 = tr16<0>(oaddr);     // ch = quad*8 + 0..3, pixel q = wave*16+lo
    bf16x4 e1 = tr16<128>(oaddr);   // ch = quad*8 + 4..7
    asm volatile("s_waitcnt lgkmcnt(0)" ::: "memory");
    __builtin_amdgcn_sched_barrier(0);
    {
        size_t gbase = (size_t)(((b * 56) + qy) * 56 + qx) * 256 + head * 32 + quad * 8;
        bf16x8 lp = *reinterpret_cast<const bf16x8*>(Olepe + gbase);
        bf16x8 oo;
        #pragma unroll
        for (int j = 0; j < 4; j++) {
            oo[j]     = (short)f2bf(bf2f((unsigned short)e0[j]) + bf2f((unsigned short)lp[j]));
            oo[4 + j] = (short)f2bf(bf2f((unsigned short)e1[j]) + bf2f((unsigned short)lp[4 + j]));
        }
        *reinterpret_cast<bf16x8*>(Osum + gbase) = oo;
    }
}

// ---------------------------------------------------------------------------
// K7: out proj (MFMA, double-buffered DMA): Osum[12544,256] @ Wo^T + bo.
// M-tile 64 -> 784 blocks (3.06/CU): no tail quantization (R8 lesson).
// ---------------------------------------------------------------------------
__global__ __launch_bounds__(256) void k_proj(
    const unsigned short* __restrict__ A,
    const unsigned short* __restrict__ Bt,   // Wto [256][256]
    const float* __restrict__ bias,
    float* __restrict__ O)
{
    __shared__ __align__(16) unsigned short As[2 * 64 * 32];
    __shared__ __align__(16) unsigned short Bs[2 * 64 * 32];
    const int t = threadIdx.x;
    const int m0 = blockIdx.x * 64, n0 = blockIdx.y * 64;
    const int wave = t >> 6, lane = t & 63, quad = lane >> 4, lo = lane & 15;
    const int sr = wave * 16 + (lane >> 2);
    const int sc = lane & 3;
    f32x4 acc[4];
    #pragma unroll
    for (int j = 0; j < 4; j++) acc[j] = (f32x4){0.f, 0.f, 0.f, 0.f};

    auto stage = [&](int it) {
        int kt = it * 32;
        unsigned short* Ad = As + (it & 1) * 2048;
        unsigned short* Bd = Bs + (it & 1) * 2048;
        int e = sc ^ ((sr >> 1) & 3);
        load_lds16(A  + (size_t)(m0 + sr) * 256 + kt + e * 8, &Ad[sr * 32 + sc * 8]);
        load_lds16(Bt + (size_t)(n0 + sr) * 256 + kt + e * 8, &Bd[sr * 32 + sc * 8]);
    };
    stage(0);
    for (int it = 0; it < 8; ++it) {
        if (it < 7) {
            stage(it + 1);                                   // 2 loads in flight
            asm volatile("s_waitcnt vmcnt(2)" ::: "memory");
        } else {
            asm volatile("s_waitcnt vmcnt(0)" ::: "memory");
        }
        __builtin_amdgcn_s_barrier();
        const unsigned short* Ac = As + (it & 1) * 2048;
        const unsigned short* Bc = Bs + (it & 1) * 2048;
        bf16x8 af;
        {
            int row = wave * 16 + lo;
            int c = quad ^ ((row >> 1) & 3);
            af = *reinterpret_cast<const bf16x8*>(&Ac[row * 32 + c * 8]);
        }
        bf16x8 bfr[4];
        #pragma unroll
        for (int nt = 0; nt < 4; nt++) {
            int col = nt * 16 + lo;
            int c = quad ^ ((col >> 1) & 3);
            bfr[nt] = *reinterpret_cast<const bf16x8*>(&Bc[col * 32 + c * 8]);
        }
        #pragma unroll
        for (int nt = 0; nt < 4; nt++)
            acc[nt] = __builtin_amdgcn_mfma_f32_16x16x32_bf16(af, bfr[nt], acc[nt], 0, 0, 0);
        __builtin_amdgcn_s_barrier();
    }
    float bv[4];
    #pragma unroll
    for (int nt = 0; nt < 4; nt++) bv[nt] = bias[n0 + nt * 16 + lo];
    #pragma unroll
    for (int nt = 0; nt < 4; nt++) {
        int n = n0 + nt * 16 + lo;
        #pragma unroll
        for (int r = 0; r < 4; r++) {
            int m = m0 + wave * 16 + quad * 4 + r;
            O[m * 256 + n] = acc[nt][r] + bv[nt];
        }
    }
}

// ---------------------------------------------------------------------------
extern "C" void kernel_launch(void* const* d_in, const int* in_sizes, int n_in,
                              void* d_out, int out_size, void* d_ws, size_t ws_size,
                              hipStream_t stream)
{
    const float* x    = (const float*)d_in[0];
    const float* Wqkv = (const float*)d_in[1];
    const float* bqkv = (const float*)d_in[2];
    const float* Wo   = (const float*)d_in[3];
    const float* bo   = (const float*)d_in[4];
    const float* lw   = (const float*)d_in[5];
    const float* lb   = (const float*)d_in[6];
    float* out = (float*)d_out;

    char* ws = (char*)d_ws;
    size_t off = 0;
    unsigned short* qkv   = (unsigned short*)(ws + off); off += (size_t)NPIX * 768 * 2;
    unsigned short* xb    = (unsigned short*)(ws + off); off += (size_t)NPIX * 256 * 2;
    unsigned short* Wtq   = (unsigned short*)(ws + off); off += 768 * 256 * 2;
    unsigned short* Wto   = (unsigned short*)(ws + off); off += 256 * 256 * 2;
    unsigned short* Osum  = (unsigned short*)(ws + off); off += (size_t)NPIX * 256 * 2;
    unsigned short* Olepe = (unsigned short*)(ws + off); off += (size_t)NPIX * 256 * 2;
    float* xmean = (float*)(ws + off); off += 196 * 256 * 4;
    float* qwin  = (float*)(ws + off); off += 196 * 256 * 4;
    float* kwin  = (float*)(ws + off); off += 196 * 256 * 4;
    int*   ridx  = (int*)(ws + off);   off += 196 * 4 * 4;

    k_prep <<<dim3(456),      256, 0, stream>>>(x, xb, xmean, Wqkv, Wo, Wtq, Wto);
    k_main1<<<dim3(1568),     256, 0, stream>>>(xb, Wtq, bqkv, qkv, xmean, Wqkv, qwin, kwin);
    k_main2<<<dim3(1764),     256, 0, stream>>>(qwin, kwin, ridx, qkv, lw, lb, Olepe);
    k_attn <<<dim3(49, 8, 4), 256, 0, stream>>>(qkv, ridx, Olepe, Osum);
    k_proj <<<dim3(196, 4),   256, 0, stream>>>(Osum, Wto, bo, out);
}